// Round 4
// baseline (527.169 us; speedup 1.0000x reference)
//
#include <hip/hip_runtime.h>

#define D 128
#define DA 16

// ---------------------------------------------------------------------------
// Kernel 1: h0 = x@W0 + b0 ; h1 = x@W1 + b1   (fused: x tile read once)
// ---------------------------------------------------------------------------
__global__ __launch_bounds__(256) void node_transform_kernel(
    const float* __restrict__ x, const float* __restrict__ W0, const float* __restrict__ b0,
    const float* __restrict__ W1, const float* __restrict__ b1,
    float* __restrict__ h0, float* __restrict__ h1, int N)
{
    __shared__ __align__(16) float xs[64][32];
    __shared__ __align__(16) float w0s[32][128];
    __shared__ __align__(16) float w1s[32][128];
    const int t = threadIdx.x;
    const int row0 = blockIdx.x * 64;
    const int cg = (t & 31) * 4;   // 4 output cols
    const int rg = (t >> 5) * 8;   // 8 output rows
    float4 acc0[8], acc1[8];
    #pragma unroll
    for (int i = 0; i < 8; i++) { acc0[i] = make_float4(0,0,0,0); acc1[i] = make_float4(0,0,0,0); }

    for (int kc = 0; kc < D; kc += 32) {
        #pragma unroll
        for (int i = 0; i < 2; i++) {
            int ff = t + i * 256;
            int r = ff >> 3;
            int k = (ff & 7) * 4;
            int gr = row0 + r;
            float4 v = make_float4(0,0,0,0);
            if (gr < N) v = *(const float4*)(x + (size_t)gr * D + kc + k);
            *(float4*)&xs[r][k] = v;
        }
        #pragma unroll
        for (int i = 0; i < 4; i++) {
            int ff = t + i * 256;
            int k = ff >> 5;
            int c = (ff & 31) * 4;
            *(float4*)&w0s[k][c] = *(const float4*)(W0 + (size_t)(kc + k) * D + c);
            *(float4*)&w1s[k][c] = *(const float4*)(W1 + (size_t)(kc + k) * D + c);
        }
        __syncthreads();
        #pragma unroll 4
        for (int k = 0; k < 32; k++) {
            float4 wv0 = *(float4*)&w0s[k][cg];
            float4 wv1 = *(float4*)&w1s[k][cg];
            #pragma unroll
            for (int i = 0; i < 8; i++) {
                float xv = xs[rg + i][k];
                acc0[i].x += xv * wv0.x; acc0[i].y += xv * wv0.y;
                acc0[i].z += xv * wv0.z; acc0[i].w += xv * wv0.w;
                acc1[i].x += xv * wv1.x; acc1[i].y += xv * wv1.y;
                acc1[i].z += xv * wv1.z; acc1[i].w += xv * wv1.w;
            }
        }
        __syncthreads();
    }
    const float4 bb0 = *(const float4*)(b0 + cg);
    const float4 bb1 = *(const float4*)(b1 + cg);
    #pragma unroll
    for (int i = 0; i < 8; i++) {
        int gr = row0 + rg + i;
        if (gr < N) {
            float4 o0 = make_float4(acc0[i].x + bb0.x, acc0[i].y + bb0.y,
                                    acc0[i].z + bb0.z, acc0[i].w + bb0.w);
            float4 o1 = make_float4(acc1[i].x + bb1.x, acc1[i].y + bb1.y,
                                    acc1[i].z + bb1.z, acc1[i].w + bb1.w);
            *(float4*)(h0 + (size_t)gr * D + cg) = o0;
            *(float4*)(h1 + (size_t)gr * D + cg) = o1;
        }
    }
}

// ---------------------------------------------------------------------------
// Counting sort by dst: histogram -> single-block scan -> scatter of records
// ---------------------------------------------------------------------------
__global__ __launch_bounds__(256) void hist_kernel(
    const int* __restrict__ idx, int* __restrict__ cnt, int E)
{
    const int stride = gridDim.x * blockDim.x;
    for (int e = blockIdx.x * blockDim.x + threadIdx.x; e < E; e += stride)
        atomicAdd(&cnt[idx[e]], 1);
}

__global__ __launch_bounds__(1024) void scan_kernel(
    const int* __restrict__ cnt, int* __restrict__ offs, int* __restrict__ cursor, int N)
{
    const int t = threadIdx.x;
    const int seg = (N + 1023) >> 10;
    const int base = t * seg;
    int sum = 0;
    for (int i = 0; i < seg; i++) {
        int g = base + i;
        if (g < N) sum += cnt[g];
    }
    __shared__ int tmp[1024];
    tmp[t] = sum;
    __syncthreads();
    for (int off = 1; off < 1024; off <<= 1) {
        int v = (t >= off) ? tmp[t - off] : 0;
        __syncthreads();
        tmp[t] += v;
        __syncthreads();
    }
    int run = tmp[t] - sum;   // exclusive prefix of this thread's segment
    for (int i = 0; i < seg; i++) {
        int g = base + i;
        if (g < N) {
            offs[g] = run;
            cursor[g] = run;
            run += cnt[g];
        }
    }
    if (t == 1023) offs[N] = run;   // == E
}

__global__ __launch_bounds__(256) void scatter_kernel(
    const int* __restrict__ idx, int* __restrict__ cursor, int4* __restrict__ srt, int E)
{
    const int stride = gridDim.x * blockDim.x;
    for (int e = blockIdx.x * blockDim.x + threadIdx.x; e < E; e += stride) {
        int dst = idx[e];
        int s0  = idx[(long)E + e];
        int s1  = idx[2L * E + e];
        int pos = atomicAdd(&cursor[dst], 1);
        srt[pos] = make_int4(e, s0, s1, 0);
    }
}

// ---------------------------------------------------------------------------
// Kernel 2 (pull): per node d, wave walks its dst-sorted edge bucket:
//   acc += relu(h0[s0] + h1[s1] + a[e]@Wa + ba); plain store of agg row.
// a[e] row loaded directly by every lane (wave-uniform addr -> broadcast),
// no shfl. Iterations independent -> unroll 2 overlaps two gather chains.
// ---------------------------------------------------------------------------
__global__ __launch_bounds__(256) void pull_kernel(
    const int4* __restrict__ srt, const int* __restrict__ offs,
    const float* __restrict__ a, const float* __restrict__ Wa, const float* __restrict__ ba,
    const float* __restrict__ h0, const float* __restrict__ h1,
    float* __restrict__ agg, int N)
{
    const int lane = threadIdx.x & 63;
    const int wid  = blockIdx.x * (blockDim.x >> 6) + (threadIdx.x >> 6);
    if (wid >= N) return;
    const int c2 = lane * 2;

    float2 waT[DA];
    #pragma unroll
    for (int j = 0; j < DA; j++) waT[j] = *(const float2*)(Wa + j * D + c2);
    const float2 bav = *(const float2*)(ba + c2);

    const int start = offs[wid];
    const int end   = offs[wid + 1];

    float accx = 0.0f, accy = 0.0f;

    #pragma unroll 2
    for (int ei = start; ei < end; ei++) {
        int4 rec = srt[ei];
        const float4* ap = (const float4*)(a + (size_t)rec.x * DA);
        float av[DA];
        *(float4*)&av[0]  = ap[0];
        *(float4*)&av[4]  = ap[1];
        *(float4*)&av[8]  = ap[2];
        *(float4*)&av[12] = ap[3];
        float2 h0v = *(const float2*)(h0 + (size_t)rec.y * D + c2);
        float2 h1v = *(const float2*)(h1 + (size_t)rec.z * D + c2);
        float mx = h0v.x + h1v.x + bav.x;
        float my = h0v.y + h1v.y + bav.y;
        #pragma unroll
        for (int j = 0; j < DA; j++) {
            mx += av[j] * waT[j].x;
            my += av[j] * waT[j].y;
        }
        accx += fmaxf(mx, 0.0f);
        accy += fmaxf(my, 0.0f);
    }
    *(float2*)(agg + (size_t)wid * D + c2) = make_float2(accx, accy);
}

// ---------------------------------------------------------------------------
// Kernel 3: h = x*(1+eps)+agg ; t = relu(h@W_in+b_in) ; out = t@W_out+b_out
// NOTE: agg aliases out (agg lives in d_out) — each block reads only its own
// rows (phase 1) and writes them only at the very end.
// ---------------------------------------------------------------------------
__global__ __launch_bounds__(256) void mlp_kernel(
    const float* __restrict__ x, const float* agg, const float* __restrict__ epsp,
    const float* __restrict__ Win, const float* __restrict__ bin,
    const float* __restrict__ Wout, const float* __restrict__ bout,
    float* out, int N)
{
    __shared__ __align__(16) float hs[64][32];
    __shared__ __align__(16) float ws[32][128];
    __shared__ __align__(16) float ts[64][128];
    const int t = threadIdx.x;
    const int row0 = blockIdx.x * 64;
    const int cg = (t & 31) * 4;
    const int rg = (t >> 5) * 8;
    const float epsv = 1.0f + epsp[0];
    float4 acc[8];
    #pragma unroll
    for (int i = 0; i < 8; i++) acc[i] = make_float4(0,0,0,0);

    // ---- phase 1: T = relu((x*(1+eps)+agg) @ Win + bin) ----
    for (int kc = 0; kc < D; kc += 32) {
        #pragma unroll
        for (int i = 0; i < 2; i++) {
            int ff = t + i * 256;
            int r = ff >> 3;
            int k = (ff & 7) * 4;
            int gr = row0 + r;
            float4 v = make_float4(0,0,0,0);
            if (gr < N) {
                float4 xv = *(const float4*)(x   + (size_t)gr * D + kc + k);
                float4 gv = *(const float4*)(agg + (size_t)gr * D + kc + k);
                v = make_float4(xv.x * epsv + gv.x, xv.y * epsv + gv.y,
                                xv.z * epsv + gv.z, xv.w * epsv + gv.w);
            }
            *(float4*)&hs[r][k] = v;
        }
        #pragma unroll
        for (int i = 0; i < 4; i++) {
            int ff = t + i * 256;
            int k = ff >> 5;
            int c = (ff & 31) * 4;
            *(float4*)&ws[k][c] = *(const float4*)(Win + (size_t)(kc + k) * D + c);
        }
        __syncthreads();
        #pragma unroll 4
        for (int k = 0; k < 32; k++) {
            float4 wv = *(float4*)&ws[k][cg];
            #pragma unroll
            for (int i = 0; i < 8; i++) {
                float hv = hs[rg + i][k];
                acc[i].x += hv * wv.x; acc[i].y += hv * wv.y;
                acc[i].z += hv * wv.z; acc[i].w += hv * wv.w;
            }
        }
        __syncthreads();
    }
    {
        const float4 bb = *(const float4*)(bin + cg);
        #pragma unroll
        for (int i = 0; i < 8; i++) {
            float4 tv = make_float4(fmaxf(acc[i].x + bb.x, 0.0f), fmaxf(acc[i].y + bb.y, 0.0f),
                                    fmaxf(acc[i].z + bb.z, 0.0f), fmaxf(acc[i].w + bb.w, 0.0f));
            *(float4*)&ts[rg + i][cg] = tv;
            acc[i] = make_float4(0,0,0,0);
        }
    }
    __syncthreads();

    // ---- phase 2: out = T @ Wout + bout ----
    for (int kc = 0; kc < D; kc += 32) {
        #pragma unroll
        for (int i = 0; i < 4; i++) {
            int ff = t + i * 256;
            int k = ff >> 5;
            int c = (ff & 31) * 4;
            *(float4*)&ws[k][c] = *(const float4*)(Wout + (size_t)(kc + k) * D + c);
        }
        __syncthreads();
        #pragma unroll 4
        for (int k = 0; k < 32; k++) {
            float4 wv = *(float4*)&ws[k][cg];
            #pragma unroll
            for (int i = 0; i < 8; i++) {
                float tv = ts[rg + i][kc + k];
                acc[i].x += tv * wv.x; acc[i].y += tv * wv.y;
                acc[i].z += tv * wv.z; acc[i].w += tv * wv.w;
            }
        }
        __syncthreads();
    }
    const float4 bo = *(const float4*)(bout + cg);
    #pragma unroll
    for (int i = 0; i < 8; i++) {
        int gr = row0 + rg + i;
        if (gr < N) {
            float4 o = make_float4(acc[i].x + bo.x, acc[i].y + bo.y,
                                   acc[i].z + bo.z, acc[i].w + bo.w);
            *(float4*)(out + (size_t)gr * D + cg) = o;
        }
    }
}

extern "C" void kernel_launch(void* const* d_in, const int* in_sizes, int n_in,
                              void* d_out, int out_size, void* d_ws, size_t ws_size,
                              hipStream_t stream)
{
    const float* x    = (const float*)d_in[0];
    const int*   idx  = (const int*)  d_in[1];
    const float* a    = (const float*)d_in[2];
    const float* W0   = (const float*)d_in[3];
    const float* b0   = (const float*)d_in[4];
    const float* W1   = (const float*)d_in[5];
    const float* b1   = (const float*)d_in[6];
    const float* Wa   = (const float*)d_in[7];
    const float* ba   = (const float*)d_in[8];
    const float* eps  = (const float*)d_in[9];
    const float* Win  = (const float*)d_in[10];
    const float* bin  = (const float*)d_in[11];
    const float* Wout = (const float*)d_in[12];
    const float* bout = (const float*)d_in[13];
    float* out = (float*)d_out;

    const int N = in_sizes[0] / D;
    const int E = in_sizes[1] / 3;

    // ws layout: srt records first (16B aligned), then h0/h1, then int arrays
    int4*  srt    = (int4*)d_ws;
    float* h0     = (float*)(srt + (size_t)E);
    float* h1     = h0 + (size_t)N * D;
    int*   cnt    = (int*)(h1 + (size_t)N * D);
    int*   offs   = cnt + N;
    int*   cursor = offs + N + 1;

    float* agg = out;   // agg lives in d_out; fully rewritten by pull_kernel

    hipMemsetAsync(cnt, 0, (size_t)N * sizeof(int), stream);

    const int nblk = (N + 63) / 64;
    node_transform_kernel<<<nblk, 256, 0, stream>>>(x, W0, b0, W1, b1, h0, h1, N);

    const int gsblk = 1024;
    hist_kernel<<<gsblk, 256, 0, stream>>>(idx, cnt, E);
    scan_kernel<<<1, 1024, 0, stream>>>(cnt, offs, cursor, N);
    scatter_kernel<<<gsblk, 256, 0, stream>>>(idx, cursor, srt, E);

    const int pblk = (N + 3) / 4;   // 4 waves (nodes) per 256-thread block
    pull_kernel<<<pblk, 256, 0, stream>>>(srt, offs, a, Wa, ba, h0, h1, agg, N);

    mlp_kernel<<<nblk, 256, 0, stream>>>(x, agg, eps, Win, bin, Wout, bout, out, N);
}

// Round 5
// 322.644 us; speedup vs baseline: 1.6339x; 1.6339x over previous
//
#include <hip/hip_runtime.h>

#define D 128
#define DA 16

typedef unsigned int uint;

__device__ __forceinline__ uint rne16(float f) {
    uint u = __float_as_uint(f);
    return (u + 0x7FFFu + ((u >> 16) & 1u)) >> 16;
}
__device__ __forceinline__ uint pack2(float lo, float hi) {
    return rne16(lo) | (rne16(hi) << 16);
}

// ---------------------------------------------------------------------------
// Kernel 1: h0 = x@W0 + b0 ; h1 = x@W1 + b1  -> stored as bf16 rows (256B)
// ---------------------------------------------------------------------------
__global__ __launch_bounds__(256) void node_transform_kernel(
    const float* __restrict__ x, const float* __restrict__ W0, const float* __restrict__ b0,
    const float* __restrict__ W1, const float* __restrict__ b1,
    ushort* __restrict__ h0b, ushort* __restrict__ h1b, int N)
{
    __shared__ __align__(16) float xs[64][32];
    __shared__ __align__(16) float w0s[32][128];
    __shared__ __align__(16) float w1s[32][128];
    const int t = threadIdx.x;
    const int row0 = blockIdx.x * 64;
    const int cg = (t & 31) * 4;   // 4 output cols
    const int rg = (t >> 5) * 8;   // 8 output rows
    float4 acc0[8], acc1[8];
    #pragma unroll
    for (int i = 0; i < 8; i++) { acc0[i] = make_float4(0,0,0,0); acc1[i] = make_float4(0,0,0,0); }

    for (int kc = 0; kc < D; kc += 32) {
        #pragma unroll
        for (int i = 0; i < 2; i++) {
            int ff = t + i * 256;
            int r = ff >> 3;
            int k = (ff & 7) * 4;
            int gr = row0 + r;
            float4 v = make_float4(0,0,0,0);
            if (gr < N) v = *(const float4*)(x + (size_t)gr * D + kc + k);
            *(float4*)&xs[r][k] = v;
        }
        #pragma unroll
        for (int i = 0; i < 4; i++) {
            int ff = t + i * 256;
            int k = ff >> 5;
            int c = (ff & 31) * 4;
            *(float4*)&w0s[k][c] = *(const float4*)(W0 + (size_t)(kc + k) * D + c);
            *(float4*)&w1s[k][c] = *(const float4*)(W1 + (size_t)(kc + k) * D + c);
        }
        __syncthreads();
        #pragma unroll 4
        for (int k = 0; k < 32; k++) {
            float4 wv0 = *(float4*)&w0s[k][cg];
            float4 wv1 = *(float4*)&w1s[k][cg];
            #pragma unroll
            for (int i = 0; i < 8; i++) {
                float xv = xs[rg + i][k];
                acc0[i].x += xv * wv0.x; acc0[i].y += xv * wv0.y;
                acc0[i].z += xv * wv0.z; acc0[i].w += xv * wv0.w;
                acc1[i].x += xv * wv1.x; acc1[i].y += xv * wv1.y;
                acc1[i].z += xv * wv1.z; acc1[i].w += xv * wv1.w;
            }
        }
        __syncthreads();
    }
    const float4 bb0 = *(const float4*)(b0 + cg);
    const float4 bb1 = *(const float4*)(b1 + cg);
    #pragma unroll
    for (int i = 0; i < 8; i++) {
        int gr = row0 + rg + i;
        if (gr < N) {
            *(uint2*)(h0b + (size_t)gr * D + cg) =
                make_uint2(pack2(acc0[i].x + bb0.x, acc0[i].y + bb0.y),
                           pack2(acc0[i].z + bb0.z, acc0[i].w + bb0.w));
            *(uint2*)(h1b + (size_t)gr * D + cg) =
                make_uint2(pack2(acc1[i].x + bb1.x, acc1[i].y + bb1.y),
                           pack2(acc1[i].z + bb1.z, acc1[i].w + bb1.w));
        }
    }
}

// ---------------------------------------------------------------------------
// Counting sort by dst: hist -> (block totals, scan totals, block scan) -> scatter
// ---------------------------------------------------------------------------
__global__ __launch_bounds__(256) void hist_kernel(
    const int* __restrict__ idx, int* __restrict__ cnt, int E)
{
    const int stride = gridDim.x * blockDim.x;
    for (int e = blockIdx.x * blockDim.x + threadIdx.x; e < E; e += stride)
        atomicAdd(&cnt[idx[e]], 1);
}

__global__ __launch_bounds__(1024) void block_tot_kernel(
    const int* __restrict__ cnt, int* __restrict__ btot, int N)
{
    const int t = threadIdx.x;
    const int g = blockIdx.x * 1024 + t;
    int v = (g < N) ? cnt[g] : 0;
    #pragma unroll
    for (int o = 32; o; o >>= 1) v += __shfl_down(v, o);
    __shared__ int s[16];
    if ((t & 63) == 0) s[t >> 6] = v;
    __syncthreads();
    if (t == 0) {
        int x = 0;
        #pragma unroll
        for (int i = 0; i < 16; i++) x += s[i];
        btot[blockIdx.x] = x;
    }
}

__global__ __launch_bounds__(1024) void scan_tot_kernel(int* __restrict__ btot, int nb)
{
    __shared__ int s[1024];
    const int t = threadIdx.x;
    int v = (t < nb) ? btot[t] : 0;
    s[t] = v;
    __syncthreads();
    for (int o = 1; o < 1024; o <<= 1) {
        int x = (t >= o) ? s[t - o] : 0;
        __syncthreads();
        s[t] += x;
        __syncthreads();
    }
    if (t < nb) btot[t] = s[t] - v;   // exclusive prefix of block totals
}

__global__ __launch_bounds__(1024) void scan_block_kernel(
    const int* __restrict__ cnt, const int* __restrict__ btot,
    int* __restrict__ offs, int* __restrict__ cursor, int N)
{
    __shared__ int tmp[1024];
    const int t = threadIdx.x;
    const int g = blockIdx.x * 1024 + t;
    int v = (g < N) ? cnt[g] : 0;
    tmp[t] = v;
    __syncthreads();
    for (int o = 1; o < 1024; o <<= 1) {
        int x = (t >= o) ? tmp[t - o] : 0;
        __syncthreads();
        tmp[t] += x;
        __syncthreads();
    }
    int excl = btot[blockIdx.x] + tmp[t] - v;
    if (g < N) { offs[g] = excl; cursor[g] = excl; }
    if (g == N - 1) offs[N] = excl + v;   // == E
}

__global__ __launch_bounds__(256) void scatter_kernel(
    const int* __restrict__ idx, int* __restrict__ cursor, int4* __restrict__ srt, int E)
{
    const int stride = gridDim.x * blockDim.x;
    for (int e = blockIdx.x * blockDim.x + threadIdx.x; e < E; e += stride) {
        int dst = idx[e];
        int s0  = idx[(long)E + e];
        int s1  = idx[2L * E + e];
        int pos = atomicAdd(&cursor[dst], 1);
        srt[pos] = make_int4(e, s0, s1, 0);
    }
}

// ---------------------------------------------------------------------------
// Kernel 2 (pull): per node d, wave walks its dst-sorted edge bucket:
//   acc += relu(bf16(h0[s0]) + bf16(h1[s1]) + a[e]@Wa + ba); plain agg store.
// bf16 h-tables halve the L2-miss gather traffic (the measured bottleneck).
// Uniform values readfirstlane'd so srt/a loads scalarize (s_load).
// ---------------------------------------------------------------------------
__global__ __launch_bounds__(256) void pull_kernel(
    const int4* __restrict__ srt, const int* __restrict__ offs,
    const float* __restrict__ a, const float* __restrict__ Wa, const float* __restrict__ ba,
    const ushort* __restrict__ h0b, const ushort* __restrict__ h1b,
    float* __restrict__ agg, int N)
{
    const int lane = threadIdx.x & 63;
    const int wid  = blockIdx.x * (blockDim.x >> 6) + (threadIdx.x >> 6);
    if (wid >= N) return;
    const int c2 = lane * 2;

    float2 waT[DA];
    #pragma unroll
    for (int j = 0; j < DA; j++) waT[j] = *(const float2*)(Wa + j * D + c2);
    const float2 bav = *(const float2*)(ba + c2);

    const int start = __builtin_amdgcn_readfirstlane(offs[wid]);
    const int end   = __builtin_amdgcn_readfirstlane(offs[wid + 1]);

    float accx = 0.0f, accy = 0.0f;

    #pragma unroll 2
    for (int ei = start; ei < end; ei++) {
        int4 rec = srt[ei];
        const int e_u = __builtin_amdgcn_readfirstlane(rec.x);
        const float4* ap = (const float4*)(a + (size_t)e_u * DA);
        float av[DA];
        *(float4*)&av[0]  = ap[0];
        *(float4*)&av[4]  = ap[1];
        *(float4*)&av[8]  = ap[2];
        *(float4*)&av[12] = ap[3];
        uint u0 = *(const uint*)(h0b + (size_t)rec.y * D + c2);
        uint u1 = *(const uint*)(h1b + (size_t)rec.z * D + c2);
        float mx = __uint_as_float(u0 << 16)        + __uint_as_float(u1 << 16)        + bav.x;
        float my = __uint_as_float(u0 & 0xFFFF0000u) + __uint_as_float(u1 & 0xFFFF0000u) + bav.y;
        #pragma unroll
        for (int j = 0; j < DA; j++) {
            mx += av[j] * waT[j].x;
            my += av[j] * waT[j].y;
        }
        accx += fmaxf(mx, 0.0f);
        accy += fmaxf(my, 0.0f);
    }
    *(float2*)(agg + (size_t)wid * D + c2) = make_float2(accx, accy);
}

// ---------------------------------------------------------------------------
// Kernel 3: h = x*(1+eps)+agg ; t = relu(h@W_in+b_in) ; out = t@W_out+b_out
// agg aliases out (agg lives in d_out) — block reads only its own rows.
// ---------------------------------------------------------------------------
__global__ __launch_bounds__(256) void mlp_kernel(
    const float* __restrict__ x, const float* agg, const float* __restrict__ epsp,
    const float* __restrict__ Win, const float* __restrict__ bin,
    const float* __restrict__ Wout, const float* __restrict__ bout,
    float* out, int N)
{
    __shared__ __align__(16) float hs[64][32];
    __shared__ __align__(16) float ws[32][128];
    __shared__ __align__(16) float ts[64][128];
    const int t = threadIdx.x;
    const int row0 = blockIdx.x * 64;
    const int cg = (t & 31) * 4;
    const int rg = (t >> 5) * 8;
    const float epsv = 1.0f + epsp[0];
    float4 acc[8];
    #pragma unroll
    for (int i = 0; i < 8; i++) acc[i] = make_float4(0,0,0,0);

    // ---- phase 1: T = relu((x*(1+eps)+agg) @ Win + bin) ----
    for (int kc = 0; kc < D; kc += 32) {
        #pragma unroll
        for (int i = 0; i < 2; i++) {
            int ff = t + i * 256;
            int r = ff >> 3;
            int k = (ff & 7) * 4;
            int gr = row0 + r;
            float4 v = make_float4(0,0,0,0);
            if (gr < N) {
                float4 xv = *(const float4*)(x   + (size_t)gr * D + kc + k);
                float4 gv = *(const float4*)(agg + (size_t)gr * D + kc + k);
                v = make_float4(xv.x * epsv + gv.x, xv.y * epsv + gv.y,
                                xv.z * epsv + gv.z, xv.w * epsv + gv.w);
            }
            *(float4*)&hs[r][k] = v;
        }
        #pragma unroll
        for (int i = 0; i < 4; i++) {
            int ff = t + i * 256;
            int k = ff >> 5;
            int c = (ff & 31) * 4;
            *(float4*)&ws[k][c] = *(const float4*)(Win + (size_t)(kc + k) * D + c);
        }
        __syncthreads();
        #pragma unroll 4
        for (int k = 0; k < 32; k++) {
            float4 wv = *(float4*)&ws[k][cg];
            #pragma unroll
            for (int i = 0; i < 8; i++) {
                float hv = hs[rg + i][k];
                acc[i].x += hv * wv.x; acc[i].y += hv * wv.y;
                acc[i].z += hv * wv.z; acc[i].w += hv * wv.w;
            }
        }
        __syncthreads();
    }
    {
        const float4 bb = *(const float4*)(bin + cg);
        #pragma unroll
        for (int i = 0; i < 8; i++) {
            float4 tv = make_float4(fmaxf(acc[i].x + bb.x, 0.0f), fmaxf(acc[i].y + bb.y, 0.0f),
                                    fmaxf(acc[i].z + bb.z, 0.0f), fmaxf(acc[i].w + bb.w, 0.0f));
            *(float4*)&ts[rg + i][cg] = tv;
            acc[i] = make_float4(0,0,0,0);
        }
    }
    __syncthreads();

    // ---- phase 2: out = T @ Wout + bout ----
    for (int kc = 0; kc < D; kc += 32) {
        #pragma unroll
        for (int i = 0; i < 4; i++) {
            int ff = t + i * 256;
            int k = ff >> 5;
            int c = (ff & 31) * 4;
            *(float4*)&ws[k][c] = *(const float4*)(Wout + (size_t)(kc + k) * D + c);
        }
        __syncthreads();
        #pragma unroll 4
        for (int k = 0; k < 32; k++) {
            float4 wv = *(float4*)&ws[k][cg];
            #pragma unroll
            for (int i = 0; i < 8; i++) {
                float tv = ts[rg + i][kc + k];
                acc[i].x += tv * wv.x; acc[i].y += tv * wv.y;
                acc[i].z += tv * wv.z; acc[i].w += tv * wv.w;
            }
        }
        __syncthreads();
    }
    const float4 bo = *(const float4*)(bout + cg);
    #pragma unroll
    for (int i = 0; i < 8; i++) {
        int gr = row0 + rg + i;
        if (gr < N) {
            float4 o = make_float4(acc[i].x + bo.x, acc[i].y + bo.y,
                                   acc[i].z + bo.z, acc[i].w + bo.w);
            *(float4*)(out + (size_t)gr * D + cg) = o;
        }
    }
}

extern "C" void kernel_launch(void* const* d_in, const int* in_sizes, int n_in,
                              void* d_out, int out_size, void* d_ws, size_t ws_size,
                              hipStream_t stream)
{
    const float* x    = (const float*)d_in[0];
    const int*   idx  = (const int*)  d_in[1];
    const float* a    = (const float*)d_in[2];
    const float* W0   = (const float*)d_in[3];
    const float* b0   = (const float*)d_in[4];
    const float* W1   = (const float*)d_in[5];
    const float* b1   = (const float*)d_in[6];
    const float* Wa   = (const float*)d_in[7];
    const float* ba   = (const float*)d_in[8];
    const float* eps  = (const float*)d_in[9];
    const float* Win  = (const float*)d_in[10];
    const float* bin  = (const float*)d_in[11];
    const float* Wout = (const float*)d_in[12];
    const float* bout = (const float*)d_in[13];
    float* out = (float*)d_out;

    const int N = in_sizes[0] / D;
    const int E = in_sizes[1] / 3;
    const int NB = (N + 1023) / 1024;

    // ws layout: srt | h0b | h1b | cnt | offs | cursor | btot
    int4*   srt    = (int4*)d_ws;
    ushort* h0b    = (ushort*)(srt + (size_t)E);
    ushort* h1b    = h0b + (size_t)N * D;
    int*    cnt    = (int*)(h1b + (size_t)N * D);
    int*    offs   = cnt + N;
    int*    cursor = offs + N + 1;
    int*    btot   = cursor + N;

    float* agg = out;   // agg lives in d_out; fully rewritten by pull_kernel

    hipMemsetAsync(cnt, 0, (size_t)N * sizeof(int), stream);

    const int nblk = (N + 63) / 64;
    node_transform_kernel<<<nblk, 256, 0, stream>>>(x, W0, b0, W1, b1, h0b, h1b, N);

    const int gsblk = 1024;
    hist_kernel<<<gsblk, 256, 0, stream>>>(idx, cnt, E);
    block_tot_kernel<<<NB, 1024, 0, stream>>>(cnt, btot, N);
    scan_tot_kernel<<<1, 1024, 0, stream>>>(btot, NB);
    scan_block_kernel<<<NB, 1024, 0, stream>>>(cnt, btot, offs, cursor, N);
    scatter_kernel<<<gsblk, 256, 0, stream>>>(idx, cursor, srt, E);

    const int pblk = (N + 3) / 4;   // 4 waves (nodes) per 256-thread block
    pull_kernel<<<pblk, 256, 0, stream>>>(srt, offs, a, Wa, ba, h0b, h1b, agg, N);

    mlp_kernel<<<nblk, 256, 0, stream>>>(x, agg, eps, Win, bin, Wout, bout, out, N);
}

// Round 6
// 297.317 us; speedup vs baseline: 1.7731x; 1.0852x over previous
//
#include <hip/hip_runtime.h>

#define D 128
#define DA 16

typedef unsigned int uint;
typedef __attribute__((ext_vector_type(8))) short bf16x8;
typedef __attribute__((ext_vector_type(4))) float f32x4;

__device__ __forceinline__ uint rne16(float f) {
    uint u = __float_as_uint(f);
    return (u + 0x7FFFu + ((u >> 16) & 1u)) >> 16;
}
__device__ __forceinline__ uint pack2(float lo, float hi) {
    return rne16(lo) | (rne16(hi) << 16);
}

// ---------------------------------------------------------------------------
// Kernel 1 (MFMA): h0 = bf16(x@W0 + b0) ; h1 = bf16(x@W1 + b1)
// 64 rows/block, 4 waves (16 rows each), 16x16x32 bf16 MFMA, K chunked by 32.
// W chunks staged transposed in LDS as bf16 [col][k] (pad 40 -> 2-way banks).
// A-frag: 8 consecutive k from global x (wave covers 16 rows x 128B).
// ---------------------------------------------------------------------------
__global__ __launch_bounds__(256) void node_transform_kernel(
    const float* __restrict__ x, const float* __restrict__ W0, const float* __restrict__ b0,
    const float* __restrict__ W1, const float* __restrict__ b1,
    ushort* __restrict__ h0b, ushort* __restrict__ h1b, int N)
{
    __shared__ __align__(16) short wt0[128][40];
    __shared__ __align__(16) short wt1[128][40];
    const int t = threadIdx.x;
    const int w = t >> 6;
    const int lane = t & 63;
    const int row0 = blockIdx.x * 64;
    const int arow = row0 + w * 16 + (lane & 15);
    const int asrc = (arow < N) ? arow : (N - 1);
    const int k0 = (lane >> 4) * 8;

    f32x4 acc0[8], acc1[8];
    #pragma unroll
    for (int c = 0; c < 8; c++) {
        acc0[c] = (f32x4){0.f, 0.f, 0.f, 0.f};
        acc1[c] = (f32x4){0.f, 0.f, 0.f, 0.f};
    }

    for (int kc = 0; kc < D; kc += 32) {
        #pragma unroll
        for (int i = 0; i < 4; i++) {
            int ff = t + i * 256;          // 0..1023 over 32k x 128c float4s
            int k = ff >> 5;
            int c = (ff & 31) * 4;
            float4 a0 = *(const float4*)(W0 + (size_t)(kc + k) * D + c);
            float4 a1 = *(const float4*)(W1 + (size_t)(kc + k) * D + c);
            wt0[c+0][k] = (short)rne16(a0.x); wt0[c+1][k] = (short)rne16(a0.y);
            wt0[c+2][k] = (short)rne16(a0.z); wt0[c+3][k] = (short)rne16(a0.w);
            wt1[c+0][k] = (short)rne16(a1.x); wt1[c+1][k] = (short)rne16(a1.y);
            wt1[c+2][k] = (short)rne16(a1.z); wt1[c+3][k] = (short)rne16(a1.w);
        }
        __syncthreads();
        const float* ap = x + (size_t)asrc * D + kc + k0;
        float4 v0 = *(const float4*)ap;
        float4 v1 = *(const float4*)(ap + 4);
        bf16x8 af;
        af[0]=(short)rne16(v0.x); af[1]=(short)rne16(v0.y);
        af[2]=(short)rne16(v0.z); af[3]=(short)rne16(v0.w);
        af[4]=(short)rne16(v1.x); af[5]=(short)rne16(v1.y);
        af[6]=(short)rne16(v1.z); af[7]=(short)rne16(v1.w);
        #pragma unroll
        for (int c = 0; c < 8; c++) {
            int col = c * 16 + (lane & 15);
            bf16x8 bf0 = *(const bf16x8*)&wt0[col][k0];
            bf16x8 bf1 = *(const bf16x8*)&wt1[col][k0];
            acc0[c] = __builtin_amdgcn_mfma_f32_16x16x32_bf16(af, bf0, acc0[c], 0, 0, 0);
            acc1[c] = __builtin_amdgcn_mfma_f32_16x16x32_bf16(af, bf1, acc1[c], 0, 0, 0);
        }
        __syncthreads();
    }
    const int crow0 = row0 + w * 16 + (lane >> 4) * 4;
    #pragma unroll
    for (int c = 0; c < 8; c++) {
        int col = c * 16 + (lane & 15);
        float bb0 = b0[col], bb1 = b1[col];
        #pragma unroll
        for (int r = 0; r < 4; r++) {
            int gr = crow0 + r;
            if (gr < N) {
                h0b[(size_t)gr * D + col] = (ushort)rne16(acc0[c][r] + bb0);
                h1b[(size_t)gr * D + col] = (ushort)rne16(acc1[c][r] + bb1);
            }
        }
    }
}

// ---------------------------------------------------------------------------
// Counting sort by dst: hist -> (block totals, scan totals, block scan) -> scatter
// ---------------------------------------------------------------------------
__global__ __launch_bounds__(256) void hist_kernel(
    const int* __restrict__ idx, int* __restrict__ cnt, int E)
{
    const int stride = gridDim.x * blockDim.x;
    for (int e = blockIdx.x * blockDim.x + threadIdx.x; e < E; e += stride)
        atomicAdd(&cnt[idx[e]], 1);
}

__global__ __launch_bounds__(1024) void block_tot_kernel(
    const int* __restrict__ cnt, int* __restrict__ btot, int N)
{
    const int t = threadIdx.x;
    const int g = blockIdx.x * 1024 + t;
    int v = (g < N) ? cnt[g] : 0;
    #pragma unroll
    for (int o = 32; o; o >>= 1) v += __shfl_down(v, o);
    __shared__ int s[16];
    if ((t & 63) == 0) s[t >> 6] = v;
    __syncthreads();
    if (t == 0) {
        int x = 0;
        #pragma unroll
        for (int i = 0; i < 16; i++) x += s[i];
        btot[blockIdx.x] = x;
    }
}

__global__ __launch_bounds__(1024) void scan_tot_kernel(int* __restrict__ btot, int nb)
{
    __shared__ int s[1024];
    const int t = threadIdx.x;
    int v = (t < nb) ? btot[t] : 0;
    s[t] = v;
    __syncthreads();
    for (int o = 1; o < 1024; o <<= 1) {
        int x = (t >= o) ? s[t - o] : 0;
        __syncthreads();
        s[t] += x;
        __syncthreads();
    }
    if (t < nb) btot[t] = s[t] - v;   // exclusive prefix of block totals
}

__global__ __launch_bounds__(1024) void scan_block_kernel(
    const int* __restrict__ cnt, const int* __restrict__ btot,
    int* __restrict__ offs, int* __restrict__ cursor, int N)
{
    __shared__ int tmp[1024];
    const int t = threadIdx.x;
    const int g = blockIdx.x * 1024 + t;
    int v = (g < N) ? cnt[g] : 0;
    tmp[t] = v;
    __syncthreads();
    for (int o = 1; o < 1024; o <<= 1) {
        int x = (t >= o) ? tmp[t - o] : 0;
        __syncthreads();
        tmp[t] += x;
        __syncthreads();
    }
    int excl = btot[blockIdx.x] + tmp[t] - v;
    if (g < N) { offs[g] = excl; cursor[g] = excl; }
    if (g == N - 1) offs[N] = excl + v;   // == E
}

__global__ __launch_bounds__(256) void scatter_kernel(
    const int* __restrict__ idx, int* __restrict__ cursor, int4* __restrict__ srt, int E)
{
    const int stride = gridDim.x * blockDim.x;
    for (int e = blockIdx.x * blockDim.x + threadIdx.x; e < E; e += stride) {
        int dst = idx[e];
        int s0  = idx[(long)E + e];
        int s1  = idx[2L * E + e];
        int pos = atomicAdd(&cursor[dst], 1);
        srt[pos] = make_int4(e, s0, s1, 0);
    }
}

// ---------------------------------------------------------------------------
// Kernel 2 (pull): per node d, wave walks its dst-sorted edge bucket:
//   acc += relu(bf16(h0[s0]) + bf16(h1[s1]) + a[e]@Wa + ba); plain agg store.
// ---------------------------------------------------------------------------
__global__ __launch_bounds__(256) void pull_kernel(
    const int4* __restrict__ srt, const int* __restrict__ offs,
    const float* __restrict__ a, const float* __restrict__ Wa, const float* __restrict__ ba,
    const ushort* __restrict__ h0b, const ushort* __restrict__ h1b,
    float* __restrict__ agg, int N)
{
    const int lane = threadIdx.x & 63;
    const int wid  = blockIdx.x * (blockDim.x >> 6) + (threadIdx.x >> 6);
    if (wid >= N) return;
    const int c2 = lane * 2;

    float2 waT[DA];
    #pragma unroll
    for (int j = 0; j < DA; j++) waT[j] = *(const float2*)(Wa + j * D + c2);
    const float2 bav = *(const float2*)(ba + c2);

    const int start = __builtin_amdgcn_readfirstlane(offs[wid]);
    const int end   = __builtin_amdgcn_readfirstlane(offs[wid + 1]);

    float accx = 0.0f, accy = 0.0f;

    #pragma unroll 2
    for (int ei = start; ei < end; ei++) {
        int4 rec = srt[ei];
        const int e_u = __builtin_amdgcn_readfirstlane(rec.x);
        const float4* ap = (const float4*)(a + (size_t)e_u * DA);
        float av[DA];
        *(float4*)&av[0]  = ap[0];
        *(float4*)&av[4]  = ap[1];
        *(float4*)&av[8]  = ap[2];
        *(float4*)&av[12] = ap[3];
        uint u0 = *(const uint*)(h0b + (size_t)rec.y * D + c2);
        uint u1 = *(const uint*)(h1b + (size_t)rec.z * D + c2);
        float mx = __uint_as_float(u0 << 16)         + __uint_as_float(u1 << 16)         + bav.x;
        float my = __uint_as_float(u0 & 0xFFFF0000u) + __uint_as_float(u1 & 0xFFFF0000u) + bav.y;
        #pragma unroll
        for (int j = 0; j < DA; j++) {
            mx += av[j] * waT[j].x;
            my += av[j] * waT[j].y;
        }
        accx += fmaxf(mx, 0.0f);
        accy += fmaxf(my, 0.0f);
    }
    *(float2*)(agg + (size_t)wid * D + c2) = make_float2(accx, accy);
}

// ---------------------------------------------------------------------------
// Kernel 3 (MFMA): h = x*(1+eps)+agg ; T = relu(h@W_in+b_in) ; out = T@W_out+b_out
// T kept in LDS as bf16 [64][136]. agg aliases out (own rows only).
// ---------------------------------------------------------------------------
__global__ __launch_bounds__(256) void mlp_kernel(
    const float* __restrict__ x, const float* agg, const float* __restrict__ epsp,
    const float* __restrict__ Win, const float* __restrict__ bin,
    const float* __restrict__ Wout, const float* __restrict__ bout,
    float* out, int N)
{
    __shared__ __align__(16) short wt[128][40];
    __shared__ __align__(16) short ts[64][136];
    const int t = threadIdx.x;
    const int w = t >> 6;
    const int lane = t & 63;
    const int row0 = blockIdx.x * 64;
    const int arow = row0 + w * 16 + (lane & 15);
    const int asrc = (arow < N) ? arow : (N - 1);
    const int k0 = (lane >> 4) * 8;
    const float epsv = 1.0f + epsp[0];

    f32x4 acc[8];
    #pragma unroll
    for (int c = 0; c < 8; c++) acc[c] = (f32x4){0.f, 0.f, 0.f, 0.f};

    // ---- phase 1: acc = (x*(1+eps)+agg) @ Win ----
    for (int kc = 0; kc < D; kc += 32) {
        #pragma unroll
        for (int i = 0; i < 4; i++) {
            int ff = t + i * 256;
            int k = ff >> 5;
            int c = (ff & 31) * 4;
            float4 a0 = *(const float4*)(Win + (size_t)(kc + k) * D + c);
            wt[c+0][k] = (short)rne16(a0.x); wt[c+1][k] = (short)rne16(a0.y);
            wt[c+2][k] = (short)rne16(a0.z); wt[c+3][k] = (short)rne16(a0.w);
        }
        __syncthreads();
        const float* xp = x   + (size_t)asrc * D + kc + k0;
        const float* gp = agg + (size_t)asrc * D + kc + k0;
        float4 x0 = *(const float4*)xp;
        float4 x1 = *(const float4*)(xp + 4);
        float4 g0 = *(const float4*)gp;
        float4 g1 = *(const float4*)(gp + 4);
        bf16x8 af;
        af[0]=(short)rne16(x0.x*epsv+g0.x); af[1]=(short)rne16(x0.y*epsv+g0.y);
        af[2]=(short)rne16(x0.z*epsv+g0.z); af[3]=(short)rne16(x0.w*epsv+g0.w);
        af[4]=(short)rne16(x1.x*epsv+g1.x); af[5]=(short)rne16(x1.y*epsv+g1.y);
        af[6]=(short)rne16(x1.z*epsv+g1.z); af[7]=(short)rne16(x1.w*epsv+g1.w);
        #pragma unroll
        for (int c = 0; c < 8; c++) {
            int col = c * 16 + (lane & 15);
            bf16x8 bf = *(const bf16x8*)&wt[col][k0];
            acc[c] = __builtin_amdgcn_mfma_f32_16x16x32_bf16(af, bf, acc[c], 0, 0, 0);
        }
        __syncthreads();
    }
    // ---- T = relu(acc + bin) -> LDS bf16 ----
    {
        const int trow0 = w * 16 + (lane >> 4) * 4;
        #pragma unroll
        for (int c = 0; c < 8; c++) {
            int col = c * 16 + (lane & 15);
            float bb = bin[col];
            #pragma unroll
            for (int r = 0; r < 4; r++)
                ts[trow0 + r][col] = (short)rne16(fmaxf(acc[c][r] + bb, 0.0f));
            acc[c] = (f32x4){0.f, 0.f, 0.f, 0.f};
        }
    }
    __syncthreads();

    // ---- phase 2: out = T @ Wout + bout ----
    const int trow = w * 16 + (lane & 15);
    for (int kc = 0; kc < D; kc += 32) {
        #pragma unroll
        for (int i = 0; i < 4; i++) {
            int ff = t + i * 256;
            int k = ff >> 5;
            int c = (ff & 31) * 4;
            float4 a0 = *(const float4*)(Wout + (size_t)(kc + k) * D + c);
            wt[c+0][k] = (short)rne16(a0.x); wt[c+1][k] = (short)rne16(a0.y);
            wt[c+2][k] = (short)rne16(a0.z); wt[c+3][k] = (short)rne16(a0.w);
        }
        __syncthreads();
        bf16x8 af = *(const bf16x8*)&ts[trow][kc + k0];
        #pragma unroll
        for (int c = 0; c < 8; c++) {
            int col = c * 16 + (lane & 15);
            bf16x8 bf = *(const bf16x8*)&wt[col][k0];
            acc[c] = __builtin_amdgcn_mfma_f32_16x16x32_bf16(af, bf, acc[c], 0, 0, 0);
        }
        __syncthreads();
    }
    const int crow0 = row0 + w * 16 + (lane >> 4) * 4;
    #pragma unroll
    for (int c = 0; c < 8; c++) {
        int col = c * 16 + (lane & 15);
        float bb = bout[col];
        #pragma unroll
        for (int r = 0; r < 4; r++) {
            int gr = crow0 + r;
            if (gr < N) out[(size_t)gr * D + col] = acc[c][r] + bb;
        }
    }
}

extern "C" void kernel_launch(void* const* d_in, const int* in_sizes, int n_in,
                              void* d_out, int out_size, void* d_ws, size_t ws_size,
                              hipStream_t stream)
{
    const float* x    = (const float*)d_in[0];
    const int*   idx  = (const int*)  d_in[1];
    const float* a    = (const float*)d_in[2];
    const float* W0   = (const float*)d_in[3];
    const float* b0   = (const float*)d_in[4];
    const float* W1   = (const float*)d_in[5];
    const float* b1   = (const float*)d_in[6];
    const float* Wa   = (const float*)d_in[7];
    const float* ba   = (const float*)d_in[8];
    const float* eps  = (const float*)d_in[9];
    const float* Win  = (const float*)d_in[10];
    const float* bin  = (const float*)d_in[11];
    const float* Wout = (const float*)d_in[12];
    const float* bout = (const float*)d_in[13];
    float* out = (float*)d_out;

    const int N = in_sizes[0] / D;
    const int E = in_sizes[1] / 3;
    const int NB = (N + 1023) / 1024;

    // ws layout: srt | h0b | h1b | cnt | offs | cursor | btot
    int4*   srt    = (int4*)d_ws;
    ushort* h0b    = (ushort*)(srt + (size_t)E);
    ushort* h1b    = h0b + (size_t)N * D;
    int*    cnt    = (int*)(h1b + (size_t)N * D);
    int*    offs   = cnt + N;
    int*    cursor = offs + N + 1;
    int*    btot   = cursor + N;

    float* agg = out;   // agg lives in d_out; fully rewritten by pull_kernel

    hipMemsetAsync(cnt, 0, (size_t)N * sizeof(int), stream);

    const int nblk = (N + 63) / 64;
    node_transform_kernel<<<nblk, 256, 0, stream>>>(x, W0, b0, W1, b1, h0b, h1b, N);

    const int gsblk = 1024;
    hist_kernel<<<gsblk, 256, 0, stream>>>(idx, cnt, E);
    block_tot_kernel<<<NB, 1024, 0, stream>>>(cnt, btot, N);
    scan_tot_kernel<<<1, 1024, 0, stream>>>(btot, NB);
    scan_block_kernel<<<NB, 1024, 0, stream>>>(cnt, btot, offs, cursor, N);
    scatter_kernel<<<gsblk, 256, 0, stream>>>(idx, cursor, srt, E);

    const int pblk = (N + 3) / 4;   // 4 waves (nodes) per 256-thread block
    pull_kernel<<<pblk, 256, 0, stream>>>(srt, offs, a, Wa, ba, h0b, h1b, agg, N);

    mlp_kernel<<<nblk, 256, 0, stream>>>(x, agg, eps, Win, bin, Wout, bout, out, N);
}

// Round 7
// 289.709 us; speedup vs baseline: 1.8197x; 1.0263x over previous
//
#include <hip/hip_runtime.h>

#define D 128
#define DA 16

typedef unsigned int uint;
typedef __attribute__((ext_vector_type(8))) short bf16x8;
typedef __attribute__((ext_vector_type(4))) float f32x4;

__device__ __forceinline__ uint rne16(float f) {
    uint u = __float_as_uint(f);
    return (u + 0x7FFFu + ((u >> 16) & 1u)) >> 16;
}

// ---------------------------------------------------------------------------
// Prep: transpose W0,W1,Win,Wout (128x128 f32 [k][col]) -> bf16 [col][k].
// Run once; all GEMM blocks then load B-fragments directly from global.
// ---------------------------------------------------------------------------
__global__ __launch_bounds__(256) void wtrans_kernel(
    const float* __restrict__ W0, const float* __restrict__ W1,
    const float* __restrict__ Win, const float* __restrict__ Wout,
    ushort* __restrict__ wt)
{
    int gid = blockIdx.x * 256 + threadIdx.x;   // 0..65535
    int m   = gid >> 14;
    int r   = gid & 16383;
    int col = r >> 7;
    int k   = r & 127;
    const float* W = (m == 0) ? W0 : (m == 1) ? W1 : (m == 2) ? Win : Wout;
    wt[(size_t)m * 16384 + (size_t)col * 128 + k] = (ushort)rne16(W[(size_t)k * 128 + col]);
}

// ---------------------------------------------------------------------------
// Kernel 1 (MFMA, no LDS, no barriers): h0 = bf16(x@W0+b0); h1 = bf16(x@W1+b1)
// 4 waves x 16 rows = 64 rows/block. B-frags straight from pre-transposed wt.
// ---------------------------------------------------------------------------
__global__ __launch_bounds__(256) void node_transform_kernel(
    const float* __restrict__ x,
    const ushort* __restrict__ w0t, const ushort* __restrict__ w1t,
    const float* __restrict__ b0, const float* __restrict__ b1,
    ushort* __restrict__ h0b, ushort* __restrict__ h1b, int N)
{
    const int t = threadIdx.x;
    const int w = t >> 6;
    const int lane = t & 63;
    const int lc = lane & 15;
    const int row0 = blockIdx.x * 64;
    const int arow = row0 + w * 16 + lc;
    const int asrc = (arow < N) ? arow : (N - 1);
    const int k0 = (lane >> 4) * 8;

    f32x4 acc0[8], acc1[8];
    #pragma unroll
    for (int c = 0; c < 8; c++) {
        acc0[c] = (f32x4){0.f, 0.f, 0.f, 0.f};
        acc1[c] = (f32x4){0.f, 0.f, 0.f, 0.f};
    }

    #pragma unroll
    for (int kc = 0; kc < D; kc += 32) {
        const float* ap = x + (size_t)asrc * D + kc + k0;
        float4 v0 = *(const float4*)ap;
        float4 v1 = *(const float4*)(ap + 4);
        bf16x8 af;
        af[0]=(short)rne16(v0.x); af[1]=(short)rne16(v0.y);
        af[2]=(short)rne16(v0.z); af[3]=(short)rne16(v0.w);
        af[4]=(short)rne16(v1.x); af[5]=(short)rne16(v1.y);
        af[6]=(short)rne16(v1.z); af[7]=(short)rne16(v1.w);
        #pragma unroll
        for (int c = 0; c < 8; c++) {
            int col = c * 16 + lc;
            bf16x8 bf0 = *(const bf16x8*)(w0t + (size_t)col * 128 + kc + k0);
            bf16x8 bf1 = *(const bf16x8*)(w1t + (size_t)col * 128 + kc + k0);
            acc0[c] = __builtin_amdgcn_mfma_f32_16x16x32_bf16(af, bf0, acc0[c], 0, 0, 0);
            acc1[c] = __builtin_amdgcn_mfma_f32_16x16x32_bf16(af, bf1, acc1[c], 0, 0, 0);
        }
    }
    const int crow0 = row0 + w * 16 + (lane >> 4) * 4;
    #pragma unroll
    for (int c = 0; c < 8; c++) {
        int col = c * 16 + lc;
        float bb0 = b0[col], bb1 = b1[col];
        #pragma unroll
        for (int r = 0; r < 4; r++) {
            int gr = crow0 + r;
            if (gr < N) {
                h0b[(size_t)gr * D + col] = (ushort)rne16(acc0[c][r] + bb0);
                h1b[(size_t)gr * D + col] = (ushort)rne16(acc1[c][r] + bb1);
            }
        }
    }
}

// ---------------------------------------------------------------------------
// Counting sort by dst: hist -> (block totals, scan totals, block scan) -> scatter
// ---------------------------------------------------------------------------
__global__ __launch_bounds__(256) void hist_kernel(
    const int* __restrict__ idx, int* __restrict__ cnt, int E)
{
    const int stride = gridDim.x * blockDim.x;
    for (int e = blockIdx.x * blockDim.x + threadIdx.x; e < E; e += stride)
        atomicAdd(&cnt[idx[e]], 1);
}

__global__ __launch_bounds__(1024) void block_tot_kernel(
    const int* __restrict__ cnt, int* __restrict__ btot, int N)
{
    const int t = threadIdx.x;
    const int g = blockIdx.x * 1024 + t;
    int v = (g < N) ? cnt[g] : 0;
    #pragma unroll
    for (int o = 32; o; o >>= 1) v += __shfl_down(v, o);
    __shared__ int s[16];
    if ((t & 63) == 0) s[t >> 6] = v;
    __syncthreads();
    if (t == 0) {
        int x = 0;
        #pragma unroll
        for (int i = 0; i < 16; i++) x += s[i];
        btot[blockIdx.x] = x;
    }
}

__global__ __launch_bounds__(1024) void scan_tot_kernel(int* __restrict__ btot, int nb)
{
    __shared__ int s[1024];
    const int t = threadIdx.x;
    int v = (t < nb) ? btot[t] : 0;
    s[t] = v;
    __syncthreads();
    for (int o = 1; o < 1024; o <<= 1) {
        int x = (t >= o) ? s[t - o] : 0;
        __syncthreads();
        s[t] += x;
        __syncthreads();
    }
    if (t < nb) btot[t] = s[t] - v;   // exclusive prefix of block totals
}

__global__ __launch_bounds__(1024) void scan_block_kernel(
    const int* __restrict__ cnt, const int* __restrict__ btot,
    int* __restrict__ offs, int* __restrict__ cursor, int N)
{
    __shared__ int tmp[1024];
    const int t = threadIdx.x;
    const int g = blockIdx.x * 1024 + t;
    int v = (g < N) ? cnt[g] : 0;
    tmp[t] = v;
    __syncthreads();
    for (int o = 1; o < 1024; o <<= 1) {
        int x = (t >= o) ? tmp[t - o] : 0;
        __syncthreads();
        tmp[t] += x;
        __syncthreads();
    }
    int excl = btot[blockIdx.x] + tmp[t] - v;
    if (g < N) { offs[g] = excl; cursor[g] = excl; }
    if (g == N - 1) offs[N] = excl + v;   // == E
}

// srt record: {s0 | s1<<16, e}  (N < 65536 so node ids fit 16 bits)
__global__ __launch_bounds__(256) void scatter_kernel(
    const int* __restrict__ idx, int* __restrict__ cursor, uint2* __restrict__ srt, int E)
{
    const int stride = gridDim.x * blockDim.x;
    for (int e = blockIdx.x * blockDim.x + threadIdx.x; e < E; e += stride) {
        int dst = idx[e];
        uint s0 = (uint)idx[(long)E + e];
        uint s1 = (uint)idx[2L * E + e];
        int pos = atomicAdd(&cursor[dst], 1);
        srt[pos] = make_uint2(s0 | (s1 << 16), (uint)e);
    }
}

// ---------------------------------------------------------------------------
// Kernel 2 (pull): per node d, wave walks its dst-sorted edge bucket:
//   acc += relu(bf16(h0[s0]) + bf16(h1[s1]) + a[e]@Wa + ba); plain agg store.
// All per-edge scalars readfirstlane'd -> SGPR-base gathers + s_load a rows.
// ---------------------------------------------------------------------------
__global__ __launch_bounds__(256) void pull_kernel(
    const uint2* __restrict__ srt, const int* __restrict__ offs,
    const float* __restrict__ a, const float* __restrict__ Wa, const float* __restrict__ ba,
    const ushort* __restrict__ h0b, const ushort* __restrict__ h1b,
    float* __restrict__ agg, int N)
{
    const int lane = threadIdx.x & 63;
    const int wid  = blockIdx.x * (blockDim.x >> 6) + (threadIdx.x >> 6);
    if (wid >= N) return;
    const int c2 = lane * 2;

    float2 waT[DA];
    #pragma unroll
    for (int j = 0; j < DA; j++) waT[j] = *(const float2*)(Wa + j * D + c2);
    const float2 bav = *(const float2*)(ba + c2);

    const int start = __builtin_amdgcn_readfirstlane(offs[wid]);
    const int end   = __builtin_amdgcn_readfirstlane(offs[wid + 1]);

    float accx = 0.0f, accy = 0.0f;

    #pragma unroll 2
    for (int ei = start; ei < end; ei++) {
        uint2 rec = srt[ei];
        const uint s01 = (uint)__builtin_amdgcn_readfirstlane((int)rec.x);
        const uint e_u = (uint)__builtin_amdgcn_readfirstlane((int)rec.y);
        const uint s0 = s01 & 0xFFFFu;
        const uint s1 = s01 >> 16;
        const float4* ap = (const float4*)(a + (size_t)e_u * DA);
        float av[DA];
        *(float4*)&av[0]  = ap[0];
        *(float4*)&av[4]  = ap[1];
        *(float4*)&av[8]  = ap[2];
        *(float4*)&av[12] = ap[3];
        uint u0 = *(const uint*)(h0b + (size_t)s0 * D + c2);
        uint u1 = *(const uint*)(h1b + (size_t)s1 * D + c2);
        float mx = __uint_as_float(u0 << 16)         + __uint_as_float(u1 << 16)         + bav.x;
        float my = __uint_as_float(u0 & 0xFFFF0000u) + __uint_as_float(u1 & 0xFFFF0000u) + bav.y;
        #pragma unroll
        for (int j = 0; j < DA; j++) {
            mx += av[j] * waT[j].x;
            my += av[j] * waT[j].y;
        }
        accx += fmaxf(mx, 0.0f);
        accy += fmaxf(my, 0.0f);
    }
    *(float2*)(agg + (size_t)wid * D + c2) = make_float2(accx, accy);
}

// ---------------------------------------------------------------------------
// Kernel 3 (MFMA): h = x*(1+eps)+agg ; T = relu(h@W_in+b_in) ; out = T@W_out+b_out
// B-frags direct from pre-transposed wt; only the T tile uses LDS.
// agg aliases out (own rows only; reads all precede writes via __syncthreads).
// ---------------------------------------------------------------------------
__global__ __launch_bounds__(256) void mlp_kernel(
    const float* __restrict__ x, const float* agg, const float* __restrict__ epsp,
    const ushort* __restrict__ wint, const float* __restrict__ bin,
    const ushort* __restrict__ woutt, const float* __restrict__ bout,
    float* out, int N)
{
    __shared__ __align__(16) short ts[64][136];
    const int t = threadIdx.x;
    const int w = t >> 6;
    const int lane = t & 63;
    const int lc = lane & 15;
    const int row0 = blockIdx.x * 64;
    const int arow = row0 + w * 16 + lc;
    const int asrc = (arow < N) ? arow : (N - 1);
    const int k0 = (lane >> 4) * 8;
    const float epsv = 1.0f + epsp[0];

    f32x4 acc[8];
    #pragma unroll
    for (int c = 0; c < 8; c++) acc[c] = (f32x4){0.f, 0.f, 0.f, 0.f};

    // ---- phase 1: acc = (x*(1+eps)+agg) @ Win ----
    #pragma unroll
    for (int kc = 0; kc < D; kc += 32) {
        const float* xp = x   + (size_t)asrc * D + kc + k0;
        const float* gp = agg + (size_t)asrc * D + kc + k0;
        float4 x0 = *(const float4*)xp;
        float4 x1 = *(const float4*)(xp + 4);
        float4 g0 = *(const float4*)gp;
        float4 g1 = *(const float4*)(gp + 4);
        bf16x8 af;
        af[0]=(short)rne16(x0.x*epsv+g0.x); af[1]=(short)rne16(x0.y*epsv+g0.y);
        af[2]=(short)rne16(x0.z*epsv+g0.z); af[3]=(short)rne16(x0.w*epsv+g0.w);
        af[4]=(short)rne16(x1.x*epsv+g1.x); af[5]=(short)rne16(x1.y*epsv+g1.y);
        af[6]=(short)rne16(x1.z*epsv+g1.z); af[7]=(short)rne16(x1.w*epsv+g1.w);
        #pragma unroll
        for (int c = 0; c < 8; c++) {
            int col = c * 16 + lc;
            bf16x8 bf = *(const bf16x8*)(wint + (size_t)col * 128 + kc + k0);
            acc[c] = __builtin_amdgcn_mfma_f32_16x16x32_bf16(af, bf, acc[c], 0, 0, 0);
        }
    }
    // ---- T = relu(acc + bin) -> LDS bf16 ----
    {
        const int trow0 = w * 16 + (lane >> 4) * 4;
        #pragma unroll
        for (int c = 0; c < 8; c++) {
            int col = c * 16 + lc;
            float bb = bin[col];
            #pragma unroll
            for (int r = 0; r < 4; r++)
                ts[trow0 + r][col] = (short)rne16(fmaxf(acc[c][r] + bb, 0.0f));
            acc[c] = (f32x4){0.f, 0.f, 0.f, 0.f};
        }
    }
    __syncthreads();

    // ---- phase 2: out = T @ Wout + bout ----
    const int trow = w * 16 + lc;
    #pragma unroll
    for (int kc = 0; kc < D; kc += 32) {
        bf16x8 af = *(const bf16x8*)&ts[trow][kc + k0];
        #pragma unroll
        for (int c = 0; c < 8; c++) {
            int col = c * 16 + lc;
            bf16x8 bf = *(const bf16x8*)(woutt + (size_t)col * 128 + kc + k0);
            acc[c] = __builtin_amdgcn_mfma_f32_16x16x32_bf16(af, bf, acc[c], 0, 0, 0);
        }
    }
    const int crow0 = row0 + w * 16 + (lane >> 4) * 4;
    #pragma unroll
    for (int c = 0; c < 8; c++) {
        int col = c * 16 + lc;
        float bb = bout[col];
        #pragma unroll
        for (int r = 0; r < 4; r++) {
            int gr = crow0 + r;
            if (gr < N) out[(size_t)gr * D + col] = acc[c][r] + bb;
        }
    }
}

extern "C" void kernel_launch(void* const* d_in, const int* in_sizes, int n_in,
                              void* d_out, int out_size, void* d_ws, size_t ws_size,
                              hipStream_t stream)
{
    const float* x    = (const float*)d_in[0];
    const int*   idx  = (const int*)  d_in[1];
    const float* a    = (const float*)d_in[2];
    const float* W0   = (const float*)d_in[3];
    const float* b0   = (const float*)d_in[4];
    const float* W1   = (const float*)d_in[5];
    const float* b1   = (const float*)d_in[6];
    const float* Wa   = (const float*)d_in[7];
    const float* ba   = (const float*)d_in[8];
    const float* eps  = (const float*)d_in[9];
    const float* Win  = (const float*)d_in[10];
    const float* bin  = (const float*)d_in[11];
    const float* Wout = (const float*)d_in[12];
    const float* bout = (const float*)d_in[13];
    float* out = (float*)d_out;

    const int N = in_sizes[0] / D;
    const int E = in_sizes[1] / 3;
    const int NB = (N + 1023) / 1024;

    // ws layout: srt(uint2) | h0b | h1b | cnt | offs | cursor | btot | wt
    uint2*  srt    = (uint2*)d_ws;
    ushort* h0b    = (ushort*)(srt + (size_t)E);
    ushort* h1b    = h0b + (size_t)N * D;
    int*    cnt    = (int*)(h1b + (size_t)N * D);
    int*    offs   = cnt + N;
    int*    cursor = offs + N + 1;
    int*    btot   = cursor + N;
    ushort* wt     = (ushort*)(btot + ((NB + 3) & ~3));
    ushort* w0t    = wt;
    ushort* w1t    = wt + 16384;
    ushort* wint   = wt + 2 * 16384;
    ushort* woutt  = wt + 3 * 16384;

    float* agg = out;   // agg lives in d_out; fully rewritten by pull_kernel

    hipMemsetAsync(cnt, 0, (size_t)N * sizeof(int), stream);

    wtrans_kernel<<<256, 256, 0, stream>>>(W0, W1, Win, Wout, wt);

    const int nblk = (N + 63) / 64;
    node_transform_kernel<<<nblk, 256, 0, stream>>>(x, w0t, w1t, b0, b1, h0b, h1b, N);

    const int gsblk = 1024;
    hist_kernel<<<gsblk, 256, 0, stream>>>(idx, cnt, E);
    block_tot_kernel<<<NB, 1024, 0, stream>>>(cnt, btot, N);
    scan_tot_kernel<<<1, 1024, 0, stream>>>(btot, NB);
    scan_block_kernel<<<NB, 1024, 0, stream>>>(cnt, btot, offs, cursor, N);
    scatter_kernel<<<gsblk, 256, 0, stream>>>(idx, cursor, srt, E);

    const int pblk = (N + 3) / 4;   // 4 waves (nodes) per 256-thread block
    pull_kernel<<<pblk, 256, 0, stream>>>(srt, offs, a, Wa, ba, h0b, h1b, agg, N);

    mlp_kernel<<<nblk, 256, 0, stream>>>(x, agg, eps, wint, bin, woutt, bout, out, N);
}

// Round 8
// 262.325 us; speedup vs baseline: 2.0096x; 1.1044x over previous
//
#include <hip/hip_runtime.h>

#define D 128
#define DA 16
#define CAP 64

typedef unsigned int uint;
typedef __attribute__((ext_vector_type(8))) short bf16x8;
typedef __attribute__((ext_vector_type(4))) float f32x4;

__device__ __forceinline__ uint rne16(float f) {
    uint u = __float_as_uint(f);
    return (u + 0x7FFFu + ((u >> 16) & 1u)) >> 16;
}
__device__ __forceinline__ uint pack2(float lo, float hi) {
    return rne16(lo) | (rne16(hi) << 16);
}

// ---------------------------------------------------------------------------
// Prep (fused): blocks [0,256): transpose W0,W1,Win,Wout -> bf16 [col][k].
// blocks [256,...): bucket-scatter edges by dst into fixed-capacity slots.
// srt record: {s0 | s1<<16, e}; cnt[dst] counts bucket occupancy.
// ---------------------------------------------------------------------------
__global__ __launch_bounds__(256) void prep_kernel(
    const float* __restrict__ W0, const float* __restrict__ W1,
    const float* __restrict__ Win, const float* __restrict__ Wout,
    ushort* __restrict__ wt,
    const int* __restrict__ idx, int* __restrict__ cnt,
    uint2* __restrict__ srt, int E)
{
    const int b = blockIdx.x;
    const int t = threadIdx.x;
    if (b < 256) {
        int gid = b * 256 + t;          // 0..65535 over 4 x 128 x 128
        int m   = gid >> 14;
        int r   = gid & 16383;
        int col = r >> 7;
        int k   = r & 127;
        const float* W = (m == 0) ? W0 : (m == 1) ? W1 : (m == 2) ? Win : Wout;
        wt[(size_t)m * 16384 + (size_t)col * 128 + k] =
            (ushort)rne16(W[(size_t)k * 128 + col]);
    } else {
        const int stride = (gridDim.x - 256) * 256;
        for (int e = (b - 256) * 256 + t; e < E; e += stride) {
            int dst = idx[e];
            uint s0 = (uint)idx[(long)E + e];
            uint s1 = (uint)idx[2L * E + e];
            int pos = atomicAdd(&cnt[dst], 1);
            if (pos < CAP)
                srt[(size_t)dst * CAP + pos] = make_uint2(s0 | (s1 << 16), (uint)e);
        }
    }
}

// ---------------------------------------------------------------------------
// Kernel 1 (MFMA, no LDS, no barriers): h0 = bf16(x@W0+b0); h1 = bf16(x@W1+b1)
// 4 waves x 16 rows = 64 rows/block. B-frags straight from pre-transposed wt.
// ---------------------------------------------------------------------------
__global__ __launch_bounds__(256) void node_transform_kernel(
    const float* __restrict__ x,
    const ushort* __restrict__ w0t, const ushort* __restrict__ w1t,
    const float* __restrict__ b0, const float* __restrict__ b1,
    ushort* __restrict__ h0b, ushort* __restrict__ h1b, int N)
{
    const int t = threadIdx.x;
    const int w = t >> 6;
    const int lane = t & 63;
    const int lc = lane & 15;
    const int row0 = blockIdx.x * 64;
    const int arow = row0 + w * 16 + lc;
    const int asrc = (arow < N) ? arow : (N - 1);
    const int k0 = (lane >> 4) * 8;

    f32x4 acc0[8], acc1[8];
    #pragma unroll
    for (int c = 0; c < 8; c++) {
        acc0[c] = (f32x4){0.f, 0.f, 0.f, 0.f};
        acc1[c] = (f32x4){0.f, 0.f, 0.f, 0.f};
    }

    #pragma unroll
    for (int kc = 0; kc < D; kc += 32) {
        const float* ap = x + (size_t)asrc * D + kc + k0;
        float4 v0 = *(const float4*)ap;
        float4 v1 = *(const float4*)(ap + 4);
        bf16x8 af;
        af[0]=(short)rne16(v0.x); af[1]=(short)rne16(v0.y);
        af[2]=(short)rne16(v0.z); af[3]=(short)rne16(v0.w);
        af[4]=(short)rne16(v1.x); af[5]=(short)rne16(v1.y);
        af[6]=(short)rne16(v1.z); af[7]=(short)rne16(v1.w);
        #pragma unroll
        for (int c = 0; c < 8; c++) {
            int col = c * 16 + lc;
            bf16x8 bf0 = *(const bf16x8*)(w0t + (size_t)col * 128 + kc + k0);
            bf16x8 bf1 = *(const bf16x8*)(w1t + (size_t)col * 128 + kc + k0);
            acc0[c] = __builtin_amdgcn_mfma_f32_16x16x32_bf16(af, bf0, acc0[c], 0, 0, 0);
            acc1[c] = __builtin_amdgcn_mfma_f32_16x16x32_bf16(af, bf1, acc1[c], 0, 0, 0);
        }
    }
    const int crow0 = row0 + w * 16 + (lane >> 4) * 4;
    #pragma unroll
    for (int c = 0; c < 8; c++) {
        int col = c * 16 + lc;
        float bb0 = b0[col], bb1 = b1[col];
        #pragma unroll
        for (int r = 0; r < 4; r++) {
            int gr = crow0 + r;
            if (gr < N) {
                h0b[(size_t)gr * D + col] = (ushort)rne16(acc0[c][r] + bb0);
                h1b[(size_t)gr * D + col] = (ushort)rne16(acc1[c][r] + bb1);
            }
        }
    }
}

// ---------------------------------------------------------------------------
// Kernel 2 (pull): per node d, wave walks its edge bucket:
//   acc += relu(bf16(h0[s0]) + bf16(h1[s1]) + a[e]@Wa + ba);
// bf16 agg store (12.8 MB instead of 25.6).
// ---------------------------------------------------------------------------
__global__ __launch_bounds__(256) void pull_kernel(
    const uint2* __restrict__ srt, const int* __restrict__ cnt,
    const float* __restrict__ a, const float* __restrict__ Wa, const float* __restrict__ ba,
    const ushort* __restrict__ h0b, const ushort* __restrict__ h1b,
    ushort* __restrict__ aggb, int N)
{
    const int lane = threadIdx.x & 63;
    const int wid  = blockIdx.x * (blockDim.x >> 6) + (threadIdx.x >> 6);
    if (wid >= N) return;
    const int c2 = lane * 2;

    float2 waT[DA];
    #pragma unroll
    for (int j = 0; j < DA; j++) waT[j] = *(const float2*)(Wa + j * D + c2);
    const float2 bav = *(const float2*)(ba + c2);

    int deg = __builtin_amdgcn_readfirstlane(cnt[wid]);
    if (deg > CAP) deg = CAP;
    const uint2* bp = srt + (size_t)wid * CAP;

    float accx = 0.0f, accy = 0.0f;

    #pragma unroll 2
    for (int i = 0; i < deg; i++) {
        uint2 rec = bp[i];
        const uint s01 = (uint)__builtin_amdgcn_readfirstlane((int)rec.x);
        const uint e_u = (uint)__builtin_amdgcn_readfirstlane((int)rec.y);
        const uint s0 = s01 & 0xFFFFu;
        const uint s1 = s01 >> 16;
        const float4* ap = (const float4*)(a + (size_t)e_u * DA);
        float av[DA];
        *(float4*)&av[0]  = ap[0];
        *(float4*)&av[4]  = ap[1];
        *(float4*)&av[8]  = ap[2];
        *(float4*)&av[12] = ap[3];
        uint u0 = *(const uint*)(h0b + (size_t)s0 * D + c2);
        uint u1 = *(const uint*)(h1b + (size_t)s1 * D + c2);
        float mx = __uint_as_float(u0 << 16)         + __uint_as_float(u1 << 16)         + bav.x;
        float my = __uint_as_float(u0 & 0xFFFF0000u) + __uint_as_float(u1 & 0xFFFF0000u) + bav.y;
        #pragma unroll
        for (int j = 0; j < DA; j++) {
            mx += av[j] * waT[j].x;
            my += av[j] * waT[j].y;
        }
        accx += fmaxf(mx, 0.0f);
        accy += fmaxf(my, 0.0f);
    }
    *(uint*)(aggb + (size_t)wid * D + c2) = pack2(accx, accy);
}

// ---------------------------------------------------------------------------
// Kernel 3 (MFMA): h = x*(1+eps)+agg ; T = relu(h@W_in+b_in) ; out = T@W_out+b_out
// agg read as bf16; B-frags direct from pre-transposed wt; T tile in LDS.
// ---------------------------------------------------------------------------
__global__ __launch_bounds__(256) void mlp_kernel(
    const float* __restrict__ x, const ushort* __restrict__ aggb,
    const float* __restrict__ epsp,
    const ushort* __restrict__ wint, const float* __restrict__ bin,
    const ushort* __restrict__ woutt, const float* __restrict__ bout,
    float* __restrict__ out, int N)
{
    __shared__ __align__(16) short ts[64][136];
    const int t = threadIdx.x;
    const int w = t >> 6;
    const int lane = t & 63;
    const int lc = lane & 15;
    const int row0 = blockIdx.x * 64;
    const int arow = row0 + w * 16 + lc;
    const int asrc = (arow < N) ? arow : (N - 1);
    const int k0 = (lane >> 4) * 8;
    const float epsv = 1.0f + epsp[0];

    f32x4 acc[8];
    #pragma unroll
    for (int c = 0; c < 8; c++) acc[c] = (f32x4){0.f, 0.f, 0.f, 0.f};

    // ---- phase 1: acc = (x*(1+eps)+agg) @ Win ----
    #pragma unroll
    for (int kc = 0; kc < D; kc += 32) {
        const float* xp = x + (size_t)asrc * D + kc + k0;
        float4 x0 = *(const float4*)xp;
        float4 x1 = *(const float4*)(xp + 4);
        uint4 g = *(const uint4*)(aggb + (size_t)asrc * D + kc + k0);
        bf16x8 af;
        af[0]=(short)rne16(x0.x*epsv + __uint_as_float(g.x << 16));
        af[1]=(short)rne16(x0.y*epsv + __uint_as_float(g.x & 0xFFFF0000u));
        af[2]=(short)rne16(x0.z*epsv + __uint_as_float(g.y << 16));
        af[3]=(short)rne16(x0.w*epsv + __uint_as_float(g.y & 0xFFFF0000u));
        af[4]=(short)rne16(x1.x*epsv + __uint_as_float(g.z << 16));
        af[5]=(short)rne16(x1.y*epsv + __uint_as_float(g.z & 0xFFFF0000u));
        af[6]=(short)rne16(x1.z*epsv + __uint_as_float(g.w << 16));
        af[7]=(short)rne16(x1.w*epsv + __uint_as_float(g.w & 0xFFFF0000u));
        #pragma unroll
        for (int c = 0; c < 8; c++) {
            int col = c * 16 + lc;
            bf16x8 bf = *(const bf16x8*)(wint + (size_t)col * 128 + kc + k0);
            acc[c] = __builtin_amdgcn_mfma_f32_16x16x32_bf16(af, bf, acc[c], 0, 0, 0);
        }
    }
    // ---- T = relu(acc + bin) -> LDS bf16 ----
    {
        const int trow0 = w * 16 + (lane >> 4) * 4;
        #pragma unroll
        for (int c = 0; c < 8; c++) {
            int col = c * 16 + lc;
            float bb = bin[col];
            #pragma unroll
            for (int r = 0; r < 4; r++)
                ts[trow0 + r][col] = (short)rne16(fmaxf(acc[c][r] + bb, 0.0f));
            acc[c] = (f32x4){0.f, 0.f, 0.f, 0.f};
        }
    }
    __syncthreads();

    // ---- phase 2: out = T @ Wout + bout ----
    const int trow = w * 16 + lc;
    #pragma unroll
    for (int kc = 0; kc < D; kc += 32) {
        bf16x8 af = *(const bf16x8*)&ts[trow][kc + k0];
        #pragma unroll
        for (int c = 0; c < 8; c++) {
            int col = c * 16 + lc;
            bf16x8 bf = *(const bf16x8*)(woutt + (size_t)col * 128 + kc + k0);
            acc[c] = __builtin_amdgcn_mfma_f32_16x16x32_bf16(af, bf, acc[c], 0, 0, 0);
        }
    }
    const int crow0 = row0 + w * 16 + (lane >> 4) * 4;
    #pragma unroll
    for (int c = 0; c < 8; c++) {
        int col = c * 16 + lc;
        float bb = bout[col];
        #pragma unroll
        for (int r = 0; r < 4; r++) {
            int gr = crow0 + r;
            if (gr < N) out[(size_t)gr * D + col] = acc[c][r] + bb;
        }
    }
}

extern "C" void kernel_launch(void* const* d_in, const int* in_sizes, int n_in,
                              void* d_out, int out_size, void* d_ws, size_t ws_size,
                              hipStream_t stream)
{
    const float* x    = (const float*)d_in[0];
    const int*   idx  = (const int*)  d_in[1];
    const float* a    = (const float*)d_in[2];
    const float* W0   = (const float*)d_in[3];
    const float* b0   = (const float*)d_in[4];
    const float* W1   = (const float*)d_in[5];
    const float* b1   = (const float*)d_in[6];
    const float* Wa   = (const float*)d_in[7];
    const float* ba   = (const float*)d_in[8];
    const float* eps  = (const float*)d_in[9];
    const float* Win  = (const float*)d_in[10];
    const float* bin  = (const float*)d_in[11];
    const float* Wout = (const float*)d_in[12];
    const float* bout = (const float*)d_in[13];
    float* out = (float*)d_out;

    const int N = in_sizes[0] / D;
    const int E = in_sizes[1] / 3;

    // ws layout: srt(uint2, N*CAP) | h0b | h1b | aggb | cnt | wt
    uint2*  srt  = (uint2*)d_ws;
    ushort* h0b  = (ushort*)(srt + (size_t)N * CAP);
    ushort* h1b  = h0b + (size_t)N * D;
    ushort* aggb = h1b + (size_t)N * D;
    int*    cnt  = (int*)(aggb + (size_t)N * D);
    ushort* wt   = (ushort*)(cnt + ((N + 3) & ~3));
    ushort* w0t   = wt;
    ushort* w1t   = wt + 16384;
    ushort* wint  = wt + 2 * 16384;
    ushort* woutt = wt + 3 * 16384;

    hipMemsetAsync(cnt, 0, (size_t)N * sizeof(int), stream);

    prep_kernel<<<256 + 1024, 256, 0, stream>>>(W0, W1, Win, Wout, wt, idx, cnt, srt, E);

    const int nblk = (N + 63) / 64;
    node_transform_kernel<<<nblk, 256, 0, stream>>>(x, w0t, w1t, b0, b1, h0b, h1b, N);

    const int pblk = (N + 3) / 4;   // 4 waves (nodes) per 256-thread block
    pull_kernel<<<pblk, 256, 0, stream>>>(srt, cnt, a, Wa, ba, h0b, h1b, aggb, N);

    mlp_kernel<<<nblk, 256, 0, stream>>>(x, aggb, eps, wint, bin, woutt, bout, out, N);
}